// Round 2
// 258.831 us; speedup vs baseline: 1.0316x; 1.0316x over previous
//
#include <hip/hip_runtime.h>

#define B_SZ 1024
#define D_SZ 128
#define KTERMS 8

// native clang vector type — required by __builtin_nontemporal_store
typedef float vfloat4 __attribute__((ext_vector_type(4)));

// 64-element dot: register-resident half-row  x  LDS vector half.
// Within a wave the LDS addresses take only 2 distinct values (half 0/1)
// -> 2-way broadcast, conflict-free.
__device__ inline float dot64(const float* r, const float* v) {
    float a0 = 0.f, a1 = 0.f, a2 = 0.f, a3 = 0.f;
#pragma unroll
    for (int j = 0; j < 64; j += 8) {
        float4 v0 = *(const float4*)(v + j);
        float4 v1 = *(const float4*)(v + j + 4);
        a0 = fmaf(r[j + 0], v0.x, a0);
        a1 = fmaf(r[j + 1], v0.y, a1);
        a2 = fmaf(r[j + 2], v0.z, a2);
        a3 = fmaf(r[j + 3], v0.w, a3);
        a0 = fmaf(r[j + 4], v1.x, a0);
        a1 = fmaf(r[j + 5], v1.y, a1);
        a2 = fmaf(r[j + 6], v1.z, a2);
        a3 = fmaf(r[j + 7], v1.w, a3);
    }
    return (a0 + a1) + (a2 + a3);
}

// One block (512 threads) per batch element.
//   t 0..255   : A0 half-rows, row = t>>1, half = t&1  (64 floats in VGPRs)
//   t 256..511 : W  half-rows, row = (t>>1)&127, half = t&1
// Math:
//   Omega = h*A0 + h*s*W - (h^3/12)(A0 W - W A0),  s = t0 + h/2
//   y = expm(Omega) y0 via 8-term Taylor;
//   Omega*v = h*(A0 v) + h*s*(W v) - (h^3/12)*(A0 (W v) - W (A0 v))
__global__ void __launch_bounds__(512, 4)
magnus_kernel(const float* __restrict__ t0p, const float* __restrict__ hp,
              const float* __restrict__ y0, const float* __restrict__ A0,
              const float* __restrict__ W, float* __restrict__ out)
{
    __shared__ __align__(16) float sv[D_SZ];
    __shared__ __align__(16) float su1[D_SZ];
    __shared__ __align__(16) float su2[D_SZ];
    __shared__ __align__(16) float su3[D_SZ];
    __shared__ __align__(16) float su4[D_SZ];

    const int b = blockIdx.x;
    const int tid = threadIdx.x;
    const float h = hp[0];
    const float tb = t0p[b];
    const float SQ3_6 = 0.28867513459481287f;  // sqrt(3)/6
    const float t1 = tb + (0.5f - SQ3_6) * h;
    const float t2 = tb + (0.5f + SQ3_6) * h;

    const size_t moff = (size_t)b * (D_SZ * D_SZ);
    const float4* A0v = (const float4*)(A0 + moff);
    const float4* Wv  = (const float4*)(W + moff);
    vfloat4* o1 = (vfloat4*)(out + (size_t)B_SZ * D_SZ + moff);
    vfloat4* o2 = (vfloat4*)(out + (size_t)B_SZ * D_SZ
                                 + (size_t)B_SZ * D_SZ * D_SZ + moff);

    // ---- Phase 1: stream A0, W once (coalesced float4); emit A1, A2 ----
    // Nontemporal stores: A1/A2 are never re-read -> don't churn L2, keep
    // the A0/W lines hot for the phase-2 row re-read.
#pragma unroll 4
    for (int it = 0; it < 8; ++it) {
        int i = it * 512 + tid;  // float4 chunk index, 0..4095
        float4 a = A0v[i];
        float4 w = Wv[i];
        vfloat4 p1, p2;
        p1.x = fmaf(t1, w.x, a.x);
        p1.y = fmaf(t1, w.y, a.y);
        p1.z = fmaf(t1, w.z, a.z);
        p1.w = fmaf(t1, w.w, a.w);
        p2.x = fmaf(t2, w.x, a.x);
        p2.y = fmaf(t2, w.y, a.y);
        p2.z = fmaf(t2, w.z, a.z);
        p2.w = fmaf(t2, w.w, a.w);
        __builtin_nontemporal_store(p1, o1 + i);
        __builtin_nontemporal_store(p2, o2 + i);
    }

    // ---- Phase 2: each thread grabs a HALF row (64 floats) into VGPRs ----
    // Pair (2r, 2r+1) covers row r.  L1/L2-hot (just streamed).
    const int half = tid & 1;
    const int row  = (tid >> 1) & 127;
    const float* rbase = (tid < 256) ? (A0 + moff) : (W + moff);
    const float4* src = (const float4*)(rbase + (size_t)row * D_SZ + half * 64);
    float r[64];
#pragma unroll
    for (int j = 0; j < 16; ++j) {
        float4 q = src[j];
        r[4 * j + 0] = q.x;
        r[4 * j + 1] = q.y;
        r[4 * j + 2] = q.z;
        r[4 * j + 3] = q.w;
    }

    // ---- Phase 3: Taylor series y = sum_k Omega^k y0 / k! ----
    float yacc = 0.0f;
    if (tid < D_SZ) {
        float v = y0[(size_t)b * D_SZ + tid];
        sv[tid] = v;
        yacc = v;
    }
    __syncthreads();

    const float hs = h * (tb + 0.5f * h);           // h * s
    const float c3 = h * h * h * (1.0f / 12.0f);    // h^3 / 12

    for (int k = 1; k <= KTERMS; ++k) {
        // Round A: u1 = A0 v (t<256) | u2 = W v (t>=256)
        float a = dot64(r, sv + half * 64);
        a += __shfl_xor(a, 1);          // pair-combine, both lanes get sum
        if (tid < 256) su1[row] = a; else su2[row] = a;  // dup write, same value
        __syncthreads();
        // Round B: u3 = A0 u2 (t<256) | u4 = W u1 (t>=256)
        const float* vb = (tid < 256) ? su2 : su1;
        float c = dot64(r, vb + half * 64);
        c += __shfl_xor(c, 1);
        if (tid < 256) su3[row] = c; else su4[row] = c;
        __syncthreads();
        if (tid < D_SZ) {
            float wn = h * su1[tid] + hs * su2[tid] - c3 * (su3[tid] - su4[tid]);
            wn *= (1.0f / (float)k);
            yacc += wn;
            sv[tid] = wn;
        }
        __syncthreads();
    }

    if (tid < D_SZ) {
        out[(size_t)b * D_SZ + tid] = yacc;
    }
}

extern "C" void kernel_launch(void* const* d_in, const int* in_sizes, int n_in,
                              void* d_out, int out_size, void* d_ws, size_t ws_size,
                              hipStream_t stream) {
    const float* t0 = (const float*)d_in[0];
    const float* h  = (const float*)d_in[1];
    const float* y0 = (const float*)d_in[2];
    const float* A0 = (const float*)d_in[3];
    const float* W  = (const float*)d_in[4];
    float* out = (float*)d_out;
    magnus_kernel<<<B_SZ, 512, 0, stream>>>(t0, h, y0, A0, W, out);
}

// Round 3
// 256.290 us; speedup vs baseline: 1.0418x; 1.0099x over previous
//
#include <hip/hip_runtime.h>

#define B_SZ 1024
#define D_SZ 128
#define KTERMS 8

// native clang vector type — required by __builtin_nontemporal_store / asm "v"
typedef float vfloat4 __attribute__((ext_vector_type(4)));

// 64-element dot: VGPR-pinned half-row q[16] x LDS vector half.
// Each 32-lane half-wave reads ONE uniform LDS address per ds_read_b128
// -> pure broadcast, zero bank conflicts.
__device__ inline float dotq(const vfloat4* q, const float* v) {
    float a0 = 0.f, a1 = 0.f, a2 = 0.f, a3 = 0.f;
#pragma unroll
    for (int j = 0; j < 16; ++j) {
        vfloat4 vv = *(const vfloat4*)(v + 4 * j);
        a0 = fmaf(q[j].x, vv.x, a0);
        a1 = fmaf(q[j].y, vv.y, a1);
        a2 = fmaf(q[j].z, vv.z, a2);
        a3 = fmaf(q[j].w, vv.w, a3);
    }
    return (a0 + a1) + (a2 + a3);
}

// One block (512 threads) per batch element.
//   grp = tid>>8      : 0 -> A0 rows, 1 -> W rows
//   t8  = tid&255, half = (t8>>5)&1 (lane bit 5 -> shfl_xor(32) partner)
//   row = (t8&31) + 32*(t8>>6)   (each row owned by lane pair l, l^32)
// Math:
//   Omega = h*A0 + h*s*W - (h^3/12)(A0 W - W A0),  s = t0 + h/2
//   y = expm(Omega) y0 via 8-term Taylor;
//   Omega*v = h*(A0 v) + h*s*(W v) - (h^3/12)*(A0 (W v) - W (A0 v))
__global__ void __launch_bounds__(512, 4)
magnus_kernel(const float* __restrict__ t0p, const float* __restrict__ hp,
              const float* __restrict__ y0, const float* __restrict__ A0,
              const float* __restrict__ W, float* __restrict__ out)
{
    __shared__ __align__(16) float sv[D_SZ];
    __shared__ __align__(16) float su1[D_SZ];
    __shared__ __align__(16) float su2[D_SZ];
    __shared__ __align__(16) float su3[D_SZ];
    __shared__ __align__(16) float su4[D_SZ];

    const int b = blockIdx.x;
    const int tid = threadIdx.x;
    const float h = hp[0];
    const float tb = t0p[b];
    const float SQ3_6 = 0.28867513459481287f;  // sqrt(3)/6
    const float t1 = tb + (0.5f - SQ3_6) * h;
    const float t2 = tb + (0.5f + SQ3_6) * h;

    const size_t moff = (size_t)b * (D_SZ * D_SZ);
    const float4* A0v = (const float4*)(A0 + moff);
    const float4* Wv  = (const float4*)(W + moff);
    vfloat4* o1 = (vfloat4*)(out + (size_t)B_SZ * D_SZ + moff);
    vfloat4* o2 = (vfloat4*)(out + (size_t)B_SZ * D_SZ
                                 + (size_t)B_SZ * D_SZ * D_SZ + moff);

    // ---- Phase 1: stream A0, W once (coalesced float4); emit A1, A2 ----
    // Nontemporal stores: A1/A2 never re-read -> don't churn L2; keep A0/W
    // lines hot for the phase-2 row fetch.
#pragma unroll 8
    for (int it = 0; it < 8; ++it) {
        int i = it * 512 + tid;  // float4 chunk index, 0..4095
        float4 a = A0v[i];
        float4 w = Wv[i];
        vfloat4 p1, p2;
        p1.x = fmaf(t1, w.x, a.x);
        p1.y = fmaf(t1, w.y, a.y);
        p1.z = fmaf(t1, w.z, a.z);
        p1.w = fmaf(t1, w.w, a.w);
        p2.x = fmaf(t2, w.x, a.x);
        p2.y = fmaf(t2, w.y, a.y);
        p2.z = fmaf(t2, w.z, a.z);
        p2.w = fmaf(t2, w.w, a.w);
        __builtin_nontemporal_store(p1, o1 + i);
        __builtin_nontemporal_store(p2, o2 + i);
    }

    // ---- Phase 2: fetch a HALF row (64 floats) and PIN it in VGPRs ----
    const int grp  = tid >> 8;           // 0 = A0, 1 = W
    const int t8   = tid & 255;
    const int half = (t8 >> 5) & 1;      // lane bit 5
    const int row  = (t8 & 31) + ((t8 >> 6) << 5);
    const float* rbase = grp ? (W + moff) : (A0 + moff);
    const vfloat4* src = (const vfloat4*)(rbase + (size_t)row * D_SZ + half * 64);
    vfloat4 q[16];
#pragma unroll
    for (int j = 0; j < 16; ++j) q[j] = src[j];
    // Redefine each q[j] through empty asm: compiler can no longer
    // rematerialize the row from memory inside the k-loop (VGPR_Count=48
    // last round proved it was doing exactly that).
#pragma unroll
    for (int j = 0; j < 16; ++j) asm volatile("" : "+v"(q[j]));

    // ---- Phase 3: Taylor series y = sum_k Omega^k y0 / k! ----
    float yacc = 0.0f;
    if (tid < D_SZ) {
        float v = y0[(size_t)b * D_SZ + tid];
        sv[tid] = v;
        yacc = v;
    }
    __syncthreads();

    const float hs = h * (tb + 0.5f * h);           // h * s
    const float c3 = h * h * h * (1.0f / 12.0f);    // h^3 / 12

#pragma unroll
    for (int k = 1; k <= KTERMS; ++k) {
        // Round A: u1 = A0 v (grp 0) | u2 = W v (grp 1)
        float a = dotq(q, sv + half * 64);
        a += __shfl_xor(a, 32);          // pair-combine within wave
        if (!half) { if (grp == 0) su1[row] = a; else su2[row] = a; }
        __syncthreads();
        // Round B: u3 = A0 u2 (grp 0) | u4 = W u1 (grp 1)
        const float* vb = grp ? su1 : su2;
        float c = dotq(q, vb + half * 64);
        c += __shfl_xor(c, 32);
        if (!half) { if (grp == 0) su3[row] = c; else su4[row] = c; }
        __syncthreads();
        if (tid < D_SZ) {
            float wn = h * su1[tid] + hs * su2[tid] - c3 * (su3[tid] - su4[tid]);
            wn *= (1.0f / (float)k);     // folds to constant (k-loop unrolled)
            yacc += wn;
            sv[tid] = wn;
        }
        __syncthreads();
    }

    if (tid < D_SZ) {
        out[(size_t)b * D_SZ + tid] = yacc;
    }
}

extern "C" void kernel_launch(void* const* d_in, const int* in_sizes, int n_in,
                              void* d_out, int out_size, void* d_ws, size_t ws_size,
                              hipStream_t stream) {
    const float* t0 = (const float*)d_in[0];
    const float* h  = (const float*)d_in[1];
    const float* y0 = (const float*)d_in[2];
    const float* A0 = (const float*)d_in[3];
    const float* W  = (const float*)d_in[4];
    float* out = (float*)d_out;
    magnus_kernel<<<B_SZ, 512, 0, stream>>>(t0, h, y0, A0, W, out);
}